// Round 1
// baseline (683.129 us; speedup 1.0000x reference)
//
#include <hip/hip_runtime.h>
#include <hip/hip_bf16.h>
#include <stdint.h>

#define DEV static __device__ __forceinline__

// Problem constants
constexpr int kB = 2, kT = 16, kL = 256, kM = 512;
constexpr int kD = 1024, kH = 16, kDH = 64, kHT = 8, kROT = 32;
constexpr int kN = kT * kL;  // 4096 flattened seq for cross-attn
constexpr float kEPS = 1e-5f;
constexpr float kNEG = -1.0e9f;
constexpr float kSCALE = 0.125f;  // 1/sqrt(64)

typedef __attribute__((ext_vector_type(8))) short short8;   // 8 bf16 (guide §3)
typedef __attribute__((ext_vector_type(4))) float floatx4;
typedef __attribute__((ext_vector_type(16))) float floatx16;

DEV float b2f(__hip_bfloat16 v) { return __bfloat162float(v); }
DEV __hip_bfloat16 f2b(float v) { return __float2bfloat16(v); }
DEV float s2f(short x) {
  __hip_bfloat16_raw r; r.x = (unsigned short)x;
  return __bfloat162float(__hip_bfloat16(r));
}

// async global->LDS, 16B per lane; LDS dst = wave-uniform base + lane*16
DEV void gl2lds16(const __hip_bfloat16* g, __hip_bfloat16* l) {
  __builtin_amdgcn_global_load_lds(
      (const __attribute__((address_space(1))) void*)g,
      (__attribute__((address_space(3))) void*)l, 16, 0, 0);
}

// ---------------- fused transposes + mask conversion ----------------
struct TransArgs {
  const float* src[7];
  __hip_bfloat16* dst[7];
  const unsigned char* cmraw;
  const unsigned char* amraw;
  int* cmask;
  int* amask;
};
__constant__ const int kTKd[7] = {1024, 1024, 1024, 1024, 512, 1024, 4096};
__constant__ const int kTNd[7] = {1024, 2048, 1024, 1536, 1024, 4096, 1024};
__constant__ const int kTCum[8] = {0, 1024, 3072, 4096, 5632, 6144, 10240, 14336};

DEV int mask_val(const unsigned char* raw, int i) {
  unsigned char b1 = raw[1], b3 = raw[3];
  if (b1 == 0x3F) return ((const unsigned short*)raw)[i] != 0;       // bf16
  if (b3 == 0x3F) return ((const float*)raw)[i] != 0.0f;             // fp32
  if (b1 == 1)    return raw[i] != 0;                                // bool
  return ((const int*)raw)[i] != 0;                                  // int32
}

__global__ __launch_bounds__(256) void transpose_all(TransArgs a) {
  int id = blockIdx.x;
  if (id >= 14336) {  // mask blocks
    if (id == 14336) {
      for (int i = threadIdx.x; i < kB * kM; i += 256)
        a.cmask[i] = mask_val(a.cmraw, i);
    } else {
      if (threadIdx.x < kB * kT)
        a.amask[threadIdx.x] = mask_val(a.amraw, threadIdx.x);
    }
    return;
  }
  int seg = 0;
  #pragma unroll
  for (int s = 1; s < 7; s++) seg += (id >= kTCum[s]);
  unsigned t = id - kTCum[seg];
  int Kd = kTKd[seg], Nd = kTNd[seg];
  unsigned ntx = Nd / 32;
  int n0 = (t % ntx) * 32, k0 = (t / ntx) * 32;
  const float* W = a.src[seg];
  __hip_bfloat16* Wt = a.dst[seg];
  __shared__ float tile[32][33];
  int tx = threadIdx.x & 31, ty = threadIdx.x >> 5;
  for (int i = 0; i < 32; i += 8)
    tile[ty + i][tx] = W[(size_t)(k0 + ty + i) * Nd + n0 + tx];
  __syncthreads();
  for (int i = 0; i < 32; i += 8)
    Wt[(size_t)(n0 + ty + i) * Kd + k0 + tx] = f2b(tile[tx][ty + i]);
}

// ---------------- LayerNorm over D=1024 fp32 in, bf16 out; 1 block/row -----
DEV void ln_body(const float* xr, const float* g, const float* bb,
                 __hip_bfloat16* outr, int tid) {
  float4 xv = *(const float4*)(xr + tid * 4);
  float s = xv.x + xv.y + xv.z + xv.w;
  float s2 = xv.x * xv.x + xv.y * xv.y + xv.z * xv.z + xv.w * xv.w;
  for (int off = 32; off; off >>= 1) {
    s += __shfl_down(s, off);
    s2 += __shfl_down(s2, off);
  }
  __shared__ float rs[4], rs2[4];
  if ((tid & 63) == 0) { rs[tid >> 6] = s; rs2[tid >> 6] = s2; }
  __syncthreads();
  float ts = rs[0] + rs[1] + rs[2] + rs[3];
  float ts2 = rs2[0] + rs2[1] + rs2[2] + rs2[3];
  float mu = ts * (1.f / kD);
  float var = ts2 * (1.f / kD) - mu * mu;
  float rstd = rsqrtf(var + kEPS);
  float4 gv = *(const float4*)(g + tid * 4);
  float4 bv = *(const float4*)(bb + tid * 4);
  ushort4 o;
  o.x = __hip_bfloat16_raw(f2b((xv.x - mu) * rstd * gv.x + bv.x)).x;
  o.y = __hip_bfloat16_raw(f2b((xv.y - mu) * rstd * gv.y + bv.y)).x;
  o.z = __hip_bfloat16_raw(f2b((xv.z - mu) * rstd * gv.z + bv.z)).x;
  o.w = __hip_bfloat16_raw(f2b((xv.w - mu) * rstd * gv.w + bv.w)).x;
  *(ushort4*)(outr + tid * 4) = o;
}

__global__ __launch_bounds__(256) void ln_rows(
    const float* __restrict__ X, const float* __restrict__ g,
    const float* __restrict__ bb, __hip_bfloat16* __restrict__ out) {
  int row = blockIdx.x;
  ln_body(X + (size_t)row * kD, g, bb, out + (size_t)row * kD, threadIdx.x);
}

// fused LN over x (8192 rows) and ctx (1024 rows)
__global__ __launch_bounds__(256) void ln_rows2(
    const float* __restrict__ X, const float* __restrict__ g,
    const float* __restrict__ bb, __hip_bfloat16* __restrict__ out,
    const float* __restrict__ X2, const float* __restrict__ g2,
    const float* __restrict__ bb2, __hip_bfloat16* __restrict__ out2) {
  int row = blockIdx.x;
  if (row < 8192)
    ln_body(X + (size_t)row * kD, g, bb, out + (size_t)row * kD, threadIdx.x);
  else {
    int r = row - 8192;
    ln_body(X2 + (size_t)r * kD, g2, bb2, out2 + (size_t)r * kD, threadIdx.x);
  }
}

// ---------------- shared GEMM epilogue (32x32 C/D frag map, m74/m101) ------
DEV void gemm_epilogue(floatx16 acc[2][2], const float* bias, const float* res,
                       int gelu, void* out, int outBf16, int Nd,
                       int m0, int n0, int wm, int wn, int l32, int kg) {
  #pragma unroll
  for (int fa = 0; fa < 2; fa++) {
    #pragma unroll
    for (int fb = 0; fb < 2; fb++) {
      int col = n0 + wn + fb * 32 + l32;
      float bv = bias ? bias[col] : 0.f;
      #pragma unroll
      for (int r = 0; r < 16; r++) {
        int row = m0 + wm + fa * 32 + (r & 3) + 8 * (r >> 2) + 4 * kg;
        float v = acc[fa][fb][r] + bv;
        if (gelu) {  // gelu(x) ~= x * sigmoid(1.702 x)
          v = v * (1.f / (1.f + __expf(-1.702f * v)));
        }
        size_t o = (size_t)row * Nd + col;
        if (res) v += res[o];
        if (outBf16) ((__hip_bfloat16*)out)[o] = f2b(v);
        else         ((float*)out)[o] = v;
      }
    }
  }
}

// ---------------- legacy MFMA GEMM core: 128x128 tile, BK=64 ---------------
// Kept for kv-proj (M=1024: too few blocks for the pipelined 128x256 kernel).
DEV void gemm_body(__hip_bfloat16* As, __hip_bfloat16* Bs,
                   const __hip_bfloat16* A, const __hip_bfloat16* Bt,
                   const float* bias, const float* res, int gelu,
                   void* out, int outBf16, int Nd, int Kd, int m0, int n0) {
  int tid = threadIdx.x, wave = tid >> 6, lane = tid & 63;
  int l32 = lane & 31, kg = lane >> 5;
  int wm = (wave >> 1) * 64, wn = (wave & 1) * 64;

  int srow = wave * 32 + (lane >> 3);
  int schunk8 = (((lane & 7) ^ ((lane >> 3) & 7)) << 3);
  const __hip_bfloat16* Ag = A + (size_t)(m0 + srow) * Kd + schunk8;
  const __hip_bfloat16* Bg = Bt + (size_t)(n0 + srow) * Kd + schunk8;
  __hip_bfloat16* Al = As + wave * 32 * 64;
  __hip_bfloat16* Bl = Bs + wave * 32 * 64;

  floatx16 acc[2][2] = {};
  for (int k0 = 0; k0 < Kd; k0 += 64) {
    #pragma unroll
    for (int i = 0; i < 4; i++) {
      gl2lds16(Ag + (size_t)(i * 8) * Kd + k0, Al + i * 512);
      gl2lds16(Bg + (size_t)(i * 8) * Kd + k0, Bl + i * 512);
    }
    __syncthreads();
    #pragma unroll
    for (int ks = 0; ks < 4; ks++) {
      int c = ks * 2 + kg;
      short8 af[2], bf2[2];
      #pragma unroll
      for (int fa = 0; fa < 2; fa++) {
        int row = wm + fa * 32 + l32;
        af[fa] = *(const short8*)(&As[row * 64 + (c ^ (row & 7)) * 8]);
      }
      #pragma unroll
      for (int fb = 0; fb < 2; fb++) {
        int row = wn + fb * 32 + l32;
        bf2[fb] = *(const short8*)(&Bs[row * 64 + (c ^ (row & 7)) * 8]);
      }
      #pragma unroll
      for (int fa = 0; fa < 2; fa++)
        #pragma unroll
        for (int fb = 0; fb < 2; fb++)
          acc[fa][fb] = __builtin_amdgcn_mfma_f32_32x32x16_bf16(
              af[fa], bf2[fb], acc[fa][fb], 0, 0, 0);
    }
    __syncthreads();
  }
  gemm_epilogue(acc, bias, res, gelu, out, outBf16, Nd, m0, n0, wm, wn, l32, kg);
}

__global__ __launch_bounds__(256) void gemm_bf16(
    const __hip_bfloat16* __restrict__ A, const __hip_bfloat16* __restrict__ Bt,
    const float* __restrict__ bias, const float* __restrict__ res, int gelu,
    void* __restrict__ out, int outBf16, int Nd, int Kd) {
  __shared__ __align__(16) __hip_bfloat16 As[128 * 64];  // 16 KB
  __shared__ __align__(16) __hip_bfloat16 Bs[128 * 64];  // 16 KB
  gemm_body(As, Bs, A, Bt, bias, res, gelu, out, outBf16, Nd, Kd,
            blockIdx.x * 128, blockIdx.y * 128);
}

// ---------------- pipelined MFMA GEMM: 128x256 tile, BK=32, 4-slot ring ----
// T3+T4+T5 from the technique catalog: counted vmcnt (never 0 in steady
// state), raw s_barrier, setprio around the MFMA cluster.
// Ring liveness proof: phase t reads slot t&3; stage of tile t+3 targets slot
// (t+3)&3 == (t-1)&3, whose readers all finished before the barrier ending
// phase t-1 (each wave passed lgkmcnt(0) before that barrier). The stage is
// issued after that barrier -> its async LDS writes can never hit live data.
// Gate: 3 global_load_lds per thread per tile; vmcnt(6) at phase end leaves
// tiles t+2,t+3 in flight and guarantees tile t+1 landed; the following
// s_barrier makes that guarantee workgroup-wide. Tail drains 6 -> 3 -> 0.
// Chunk swizzle: 32-elem rows = 4 chunks of 16B; phys = chunk ^ ((row>>1)&3),
// applied on BOTH sides (pre-swizzled global source at stage + XOR on read).
__global__ __launch_bounds__(512, 2) void gemm_pipe(
    const __hip_bfloat16* __restrict__ A, const __hip_bfloat16* __restrict__ Bt,
    const float* __restrict__ bias, const float* __restrict__ res, int gelu,
    void* __restrict__ out, int outBf16, int Nd, int Kd) {
  __shared__ __align__(16) __hip_bfloat16 As[4][128 * 32];  // 32 KB
  __shared__ __align__(16) __hip_bfloat16 Bs[4][256 * 32];  // 64 KB
  const int m0 = blockIdx.x * 128, n0 = blockIdx.y * 256;
  const int tid = threadIdx.x, wave = tid >> 6, lane = tid & 63;
  const int l32 = lane & 31, kg = lane >> 5;
  const int wm = (wave >> 2) * 64, wn = (wave & 3) * 64;  // 2(M) x 4(N) waves
  const int NT = Kd >> 5;  // K-tiles of 32 (all Ks here are multiples of 32)

  // staging sources: wave w covers A rows w*16..+15, B rows w*32..+31
  const int arow = wave * 16 + (lane >> 2);                 // 0..127
  const int alc = (lane & 3) ^ ((arow >> 1) & 3);
  const __hip_bfloat16* Ag = A + (size_t)(m0 + arow) * Kd + alc * 8;
  const int brow0 = wave * 32 + (lane >> 2);                // 0..255 (i=0)
  const int brow1 = brow0 + 16;
  const int blc0 = (lane & 3) ^ ((brow0 >> 1) & 3);
  const int blc1 = (lane & 3) ^ ((brow1 >> 1) & 3);
  const __hip_bfloat16* Bg0 = Bt + (size_t)(n0 + brow0) * Kd + blc0 * 8;
  const __hip_bfloat16* Bg1 = Bt + (size_t)(n0 + brow1) * Kd + blc1 * 8;
  __hip_bfloat16* Al = &As[0][0] + wave * 512;    // + slot*4096
  __hip_bfloat16* Bl0 = &Bs[0][0] + wave * 1024;  // + slot*8192
  __hip_bfloat16* Bl1 = Bl0 + 512;

  auto stage = [&](int t) {
    int slot = t & 3, k0 = t << 5;
    gl2lds16(Ag + k0, Al + slot * 4096);
    gl2lds16(Bg0 + k0, Bl0 + slot * 8192);
    gl2lds16(Bg1 + k0, Bl1 + slot * 8192);
  };

  floatx16 acc[2][2] = {};

  // prologue: 3 tiles in flight; ensure tile 0 landed everywhere
  stage(0); stage(1); stage(2);
  asm volatile("s_waitcnt vmcnt(6)" ::: "memory");
  __builtin_amdgcn_s_barrier();
  asm volatile("" ::: "memory");

  for (int t = 0; t < NT; ++t) {
    const __hip_bfloat16* Asl = &As[t & 3][0];
    const __hip_bfloat16* Bsl = &Bs[t & 3][0];
    short8 af[2][2], bf2[2][2];
    #pragma unroll
    for (int ks = 0; ks < 2; ks++) {
      int c = ks * 2 + kg;  // logical 16B chunk (k = ks*16 + kg*8 + j)
      #pragma unroll
      for (int fa = 0; fa < 2; fa++) {
        int row = wm + fa * 32 + l32;
        af[ks][fa] = *(const short8*)(Asl + row * 32 + (c ^ ((row >> 1) & 3)) * 8);
      }
      #pragma unroll
      for (int fb = 0; fb < 2; fb++) {
        int row = wn + fb * 32 + l32;
        bf2[ks][fb] = *(const short8*)(Bsl + row * 32 + (c ^ ((row >> 1) & 3)) * 8);
      }
    }
    if (t + 3 < NT) stage(t + 3);
    __builtin_amdgcn_s_barrier();           // phase split (enables T5)
    asm volatile("s_waitcnt lgkmcnt(0)" ::: "memory");
    __builtin_amdgcn_s_setprio(1);
    #pragma unroll
    for (int ks = 0; ks < 2; ks++)
      #pragma unroll
      for (int fa = 0; fa < 2; fa++)
        #pragma unroll
        for (int fb = 0; fb < 2; fb++)
          acc[fa][fb] = __builtin_amdgcn_mfma_f32_32x32x16_bf16(
              af[ks][fa], bf2[ks][fb], acc[fa][fb], 0, 0, 0);
    __builtin_amdgcn_s_setprio(0);
    // gate tile t+1 (counted: steady state keeps 6 loads = 2 tiles in flight)
    if (t < NT - 3)       asm volatile("s_waitcnt vmcnt(6)" ::: "memory");
    else if (t == NT - 3) asm volatile("s_waitcnt vmcnt(3)" ::: "memory");
    else if (t == NT - 2) asm volatile("s_waitcnt vmcnt(0)" ::: "memory");
    __builtin_amdgcn_s_barrier();
    asm volatile("" ::: "memory");          // no ds_read hoists above the gate
    __builtin_amdgcn_sched_barrier(0);
  }

  gemm_epilogue(acc, bias, res, gelu, out, outBf16, Nd, m0, n0, wm, wn, l32, kg);
}

// ---------------- MFMA cross-attention (flash-style online softmax) --------
__global__ __launch_bounds__(256) void cross_attn_mfma(
    const __hip_bfloat16* __restrict__ Qb,   // [B*N][1024]
    const __hip_bfloat16* __restrict__ KVb,  // [B*M][2048] (k | v)
    const int* __restrict__ cmask,           // [B*M]
    __hip_bfloat16* __restrict__ Ob) {       // [B*N][1024]
  __shared__ __align__(16) __hip_bfloat16 Vbf[2][8][64][8];   // 16 KB
  __shared__ __align__(16) __hip_bfloat16 Paf[4][8][16][8];   // 8 KB
  int b = blockIdx.y >> 4, h = blockIdx.y & 15;
  int q0 = blockIdx.x * 64;
  int tid = threadIdx.x, wave = tid >> 6, lane = tid & 63;
  int l16 = lane & 15, quad = lane >> 4;

  const __hip_bfloat16* qrow =
      Qb + (size_t)(b * kN + q0 + wave * 16 + l16) * 1024 + h * 64 + quad * 8;
  short8 qf0 = *(const short8*)qrow;
  short8 qf1 = *(const short8*)(qrow + 32);

  floatx4 of[4] = {};
  float Mr[4] = {-1e30f, -1e30f, -1e30f, -1e30f};
  float Lr[4] = {};

  int skey = tid >> 2, sd0 = (tid & 3) * 16;

  for (int kt = 0; kt < 8; kt++) {
    int buf = kt & 1;
    {
      const __hip_bfloat16* src =
          KVb + (size_t)(b * kM + kt * 64 + skey) * 2048 + 1024 + h * 64 + sd0;
      short8 v0 = *(const short8*)src;
      short8 v1 = *(const short8*)(src + 8);
      int kb = skey >> 3, kj = skey & 7;
      #pragma unroll
      for (int j = 0; j < 8; j++) {
        Vbf[buf][kb][sd0 + j][kj] = __hip_bfloat16(__hip_bfloat16_raw{(unsigned short)v0[j]});
        Vbf[buf][kb][sd0 + 8 + j][kj] = __hip_bfloat16(__hip_bfloat16_raw{(unsigned short)v1[j]});
      }
    }
    __syncthreads();

    floatx4 sf[4];
    #pragma unroll
    for (int nf = 0; nf < 4; nf++) {
      const __hip_bfloat16* krow =
          KVb + (size_t)(b * kM + kt * 64 + nf * 16 + l16) * 2048 + h * 64 + quad * 8;
      short8 kf0 = *(const short8*)krow;
      short8 kf1 = *(const short8*)(krow + 32);
      floatx4 z = {};
      z = __builtin_amdgcn_mfma_f32_16x16x32_bf16(qf0, kf0, z, 0, 0, 0);
      z = __builtin_amdgcn_mfma_f32_16x16x32_bf16(qf1, kf1, z, 0, 0, 0);
      sf[nf] = z;
    }

    float sv[4][4];
    #pragma unroll
    for (int nf = 0; nf < 4; nf++) {
      int mk = cmask[b * kM + kt * 64 + nf * 16 + l16];
      #pragma unroll
      for (int r = 0; r < 4; r++)
        sv[nf][r] = mk ? sf[nf][r] * kSCALE : kNEG;
    }
    float mx[4];
    #pragma unroll
    for (int r = 0; r < 4; r++) {
      float m = fmaxf(fmaxf(sv[0][r], sv[1][r]), fmaxf(sv[2][r], sv[3][r]));
      #pragma unroll
      for (int off = 1; off < 16; off <<= 1) m = fmaxf(m, __shfl_xor(m, off));
      mx[r] = m;
    }
    float alpha[4], Mn[4];
    #pragma unroll
    for (int r = 0; r < 4; r++) {
      Mn[r] = fmaxf(Mr[r], mx[r]);
      alpha[r] = __expf(Mr[r] - Mn[r]);
      Mr[r] = Mn[r];
    }
    float p[4][4];
    float rsum[4];
    #pragma unroll
    for (int r = 0; r < 4; r++) {
      float s = 0.f;
      #pragma unroll
      for (int nf = 0; nf < 4; nf++) {
        float e = __expf(sv[nf][r] - Mn[r]);
        p[nf][r] = e; s += e;
      }
      #pragma unroll
      for (int off = 1; off < 16; off <<= 1) s += __shfl_xor(s, off);
      rsum[r] = s;
    }
    #pragma unroll
    for (int r = 0; r < 4; r++) Lr[r] = Lr[r] * alpha[r] + rsum[r];
    #pragma unroll
    for (int df = 0; df < 4; df++)
      #pragma unroll
      for (int r = 0; r < 4; r++) of[df][r] *= alpha[r];

    #pragma unroll
    for (int nf = 0; nf < 4; nf++) {
      int col = nf * 16 + l16;
      int kb = col >> 3, kj = col & 7;
      #pragma unroll
      for (int r = 0; r < 4; r++)
        Paf[wave][kb][quad * 4 + r][kj] = f2b(p[nf][r]);
    }
    __builtin_amdgcn_s_waitcnt(0);

    short8 pf0 = *(const short8*)(&Paf[wave][quad][l16][0]);
    short8 pf1 = *(const short8*)(&Paf[wave][quad + 4][l16][0]);
    #pragma unroll
    for (int df = 0; df < 4; df++) {
      short8 vf0 = *(const short8*)(&Vbf[buf][quad][df * 16 + l16][0]);
      short8 vf1 = *(const short8*)(&Vbf[buf][quad + 4][df * 16 + l16][0]);
      of[df] = __builtin_amdgcn_mfma_f32_16x16x32_bf16(pf0, vf0, of[df], 0, 0, 0);
      of[df] = __builtin_amdgcn_mfma_f32_16x16x32_bf16(pf1, vf1, of[df], 0, 0, 0);
    }
  }

  #pragma unroll
  for (int df = 0; df < 4; df++) {
    #pragma unroll
    for (int r = 0; r < 4; r++) {
      int row = q0 + wave * 16 + quad * 4 + r;
      float v = of[df][r] / Lr[r];
      Ob[(size_t)(b * kN + row) * 1024 + h * 64 + df * 16 + l16] = f2b(v);
    }
  }
}

// ---------------- temporal attention (with RoPE) ----------------
__global__ __launch_bounds__(64) void temporal_attn(
    const __hip_bfloat16* __restrict__ QKVb,  // [B*T*L][1536] (q|k|v)
    const float* __restrict__ rope,           // [T][32] fp32
    const int* __restrict__ amask,            // [B*T]
    __hip_bfloat16* __restrict__ Otb) {       // [B*T*L][512]
  __shared__ float qs[16][65], ks[16][65], vs[16][65];
  __shared__ float Ps[16][17];
  int idx = blockIdx.x;
  int h = idx & 7, l = (idx >> 3) & 255, b = idx >> 11;
  int lane = threadIdx.x;

  {  // vectorized loads: 6x short8 per thread (16B each)
    int tr = lane >> 2, c0 = (lane & 3) * 16;
    const __hip_bfloat16* base =
        QKVb + ((size_t)(b * kT + tr) * kL + l) * 1536 + h * 64;
    short8 qa = *(const short8*)(base + c0);
    short8 qb = *(const short8*)(base + c0 + 8);
    short8 ka = *(const short8*)(base + 512 + c0);
    short8 kb = *(const short8*)(base + 512 + c0 + 8);
    short8 va = *(const short8*)(base + 1024 + c0);
    short8 vb = *(const short8*)(base + 1024 + c0 + 8);
    #pragma unroll
    for (int j = 0; j < 8; j++) {
      qs[tr][c0 + j] = s2f(qa[j]) * kSCALE;
      qs[tr][c0 + 8 + j] = s2f(qb[j]) * kSCALE;
      ks[tr][c0 + j] = s2f(ka[j]);
      ks[tr][c0 + 8 + j] = s2f(kb[j]);
      vs[tr][c0 + j] = s2f(va[j]);
      vs[tr][c0 + 8 + j] = s2f(vb[j]);
    }
  }
  __syncthreads();
  {
    int rt = lane >> 2, rd0 = (lane & 3) * 8;
    float nq[8], nk[8];
    for (int j = 0; j < 8; j++) {
      int d = rd0 + j;
      float ang = rope[rt * kROT + d];
      float cv = cosf(ang), sv = sinf(ang);
      float oq = (d < 16) ? -qs[rt][d + 16] : qs[rt][d - 16];
      float ok = (d < 16) ? -ks[rt][d + 16] : ks[rt][d - 16];
      nq[j] = qs[rt][d] * cv + oq * sv;
      nk[j] = ks[rt][d] * cv + ok * sv;
    }
    __syncthreads();
    for (int j = 0; j < 8; j++) { qs[rt][rd0 + j] = nq[j]; ks[rt][rd0 + j] = nk[j]; }
  }
  __syncthreads();
  {
    int tq = lane >> 2, tk0 = (lane & 3) * 4;
    float s[4] = {0, 0, 0, 0};
    for (int d = 0; d < 64; d++) {
      float qv = qs[tq][d];
      s[0] += qv * ks[tk0 + 0][d];
      s[1] += qv * ks[tk0 + 1][d];
      s[2] += qv * ks[tk0 + 2][d];
      s[3] += qv * ks[tk0 + 3][d];
    }
    for (int jj = 0; jj < 4; jj++)
      Ps[tq][tk0 + jj] = amask[b * kT + tk0 + jj] ? s[jj] : kNEG;
  }
  __syncthreads();
  if (lane < 16) {
    float mx = -1e30f;
    for (int k = 0; k < 16; k++) mx = fmaxf(mx, Ps[lane][k]);
    float sum = 0.f;
    for (int k = 0; k < 16; k++) { float p = __expf(Ps[lane][k] - mx); Ps[lane][k] = p; sum += p; }
    float inv = 1.f / sum;
    for (int k = 0; k < 16; k++) Ps[lane][k] *= inv;
  }
  __syncthreads();
  for (int tq = 0; tq < 16; tq++) {
    float acc = 0.f;
    for (int tk = 0; tk < 16; tk++) acc += Ps[tq][tk] * vs[tk][lane];
    float qm = amask[b * kT + tq] ? 1.f : 0.f;
    Otb[((size_t)(b * kT + tq) * kL + l) * 512 + h * 64 + lane] = f2b(acc * qm);
  }
}

// ---------------- launcher ----------------
extern "C" void kernel_launch(void* const* d_in, const int* in_sizes, int n_in,
                              void* d_out, int out_size, void* d_ws, size_t ws_size,
                              hipStream_t stream) {
  const float* x       = (const float*)d_in[0];
  const float* ctx     = (const float*)d_in[1];
  const float* rope    = (const float*)d_in[2];
  const float* ca_ng   = (const float*)d_in[3];
  const float* ca_nb   = (const float*)d_in[4];
  const float* ca_cng  = (const float*)d_in[5];
  const float* ca_cnb  = (const float*)d_in[6];
  const float* ca_wq   = (const float*)d_in[7];
  const float* ca_wkv  = (const float*)d_in[8];
  const float* ca_wo   = (const float*)d_in[9];
  const float* ta_ng   = (const float*)d_in[10];
  const float* ta_nb   = (const float*)d_in[11];
  const float* ta_wqkv = (const float*)d_in[12];
  const float* ta_bqkv = (const float*)d_in[13];
  const float* ta_wo   = (const float*)d_in[14];
  const float* ff_ng   = (const float*)d_in[15];
  const float* ff_nb   = (const float*)d_in[16];
  const float* ff_w1   = (const float*)d_in[17];
  const float* ff_w2   = (const float*)d_in[18];
  const unsigned char* cmraw = (const unsigned char*)d_in[19];
  const unsigned char* amraw = (const unsigned char*)d_in[20];

  char* wsc = (char*)d_ws;
  size_t off = 0;
  auto take = [&](size_t bytes) {
    char* p = wsc + off;
    off = (off + bytes + 255) & ~(size_t)255;
    return p;
  };
  __hip_bfloat16* wqT   = (__hip_bfloat16*)take((size_t)1024 * 1024 * 2);
  __hip_bfloat16* wkvT  = (__hip_bfloat16*)take((size_t)2048 * 1024 * 2);
  __hip_bfloat16* woT   = (__hip_bfloat16*)take((size_t)1024 * 1024 * 2);
  __hip_bfloat16* wqkvT = (__hip_bfloat16*)take((size_t)1536 * 1024 * 2);
  __hip_bfloat16* tawoT = (__hip_bfloat16*)take((size_t)1024 * 512 * 2);
  __hip_bfloat16* ffw1T = (__hip_bfloat16*)take((size_t)4096 * 1024 * 2);
  __hip_bfloat16* ffw2T = (__hip_bfloat16*)take((size_t)1024 * 4096 * 2);
  __hip_bfloat16* XN  = (__hip_bfloat16*)take((size_t)8192 * 1024 * 2);
  __hip_bfloat16* CN  = (__hip_bfloat16*)take((size_t)1024 * 1024 * 2);
  __hip_bfloat16* Qb  = (__hip_bfloat16*)take((size_t)8192 * 1024 * 2);
  __hip_bfloat16* KVb = (__hip_bfloat16*)take((size_t)1024 * 2048 * 2);
  __hip_bfloat16* Ob  = (__hip_bfloat16*)take((size_t)8192 * 1024 * 2);
  float*          X1  = (float*)take((size_t)8192 * 1024 * 4);
  __hip_bfloat16* Hb  = (__hip_bfloat16*)take((size_t)8192 * 4096 * 2);
  int* cmask = (int*)take((size_t)kB * kM * 4);
  int* amask = (int*)take((size_t)kB * kT * 4);
  if (off > ws_size) return;

  __hip_bfloat16* QKVb = Hb;  // [8192][1536], dead before Hb is written
  __hip_bfloat16* OTb  = Qb;  // [8192][512], Q dead after cross_attn

  // pipelined 128x256 GEMM (M multiple of 128, N multiple of 256, K of 32)
  auto gemmP = [&](const __hip_bfloat16* A, const __hip_bfloat16* Bt,
                   const float* bias, const float* res, int gelu, void* out,
                   int outBf16, int Md, int Nd, int Kd) {
    gemm_pipe<<<dim3(Md / 128, Nd / 256), dim3(512), 0, stream>>>(
        A, Bt, bias, res, gelu, out, outBf16, Nd, Kd);
  };

  // fused transposes + masks (1 launch)
  TransArgs ta;
  ta.src[0] = ca_wq;   ta.dst[0] = wqT;
  ta.src[1] = ca_wkv;  ta.dst[1] = wkvT;
  ta.src[2] = ca_wo;   ta.dst[2] = woT;
  ta.src[3] = ta_wqkv; ta.dst[3] = wqkvT;
  ta.src[4] = ta_wo;   ta.dst[4] = tawoT;
  ta.src[5] = ff_w1;   ta.dst[5] = ffw1T;
  ta.src[6] = ff_w2;   ta.dst[6] = ffw2T;
  ta.cmraw = cmraw; ta.amraw = amraw; ta.cmask = cmask; ta.amask = amask;
  transpose_all<<<dim3(14338), dim3(256), 0, stream>>>(ta);

  // cross-attention block
  ln_rows2<<<dim3(9216), dim3(256), 0, stream>>>(x, ca_ng, ca_nb, XN,
                                                 ctx, ca_cng, ca_cnb, CN);
  gemmP(XN, wqT, nullptr, nullptr, 0, Qb, 1, 8192, 1024, 1024);       // q-proj
  gemm_bf16<<<dim3(8, 16), dim3(256), 0, stream>>>(                   // kv-proj
      CN, wkvT, nullptr, nullptr, 0, KVb, 1, 2048, 1024);
  cross_attn_mfma<<<dim3(kN / 64, kB * kH), dim3(256), 0, stream>>>(Qb, KVb, cmask, Ob);
  gemmP(Ob, woT, nullptr, x, 0, X1, 0, 8192, 1024, 1024);             // o-proj

  // temporal attention block
  ln_rows<<<dim3(8192), dim3(256), 0, stream>>>(X1, ta_ng, ta_nb, XN);
  gemmP(XN, wqkvT, ta_bqkv, nullptr, 0, QKVb, 1, 8192, 1536, 1024);   // qkv
  temporal_attn<<<dim3(kB * kL * kHT), dim3(64), 0, stream>>>(QKVb, rope, amask, OTb);
  gemmP(OTb, tawoT, nullptr, X1, 0, X1, 0, 8192, 1024, 512);          // ta_wo

  // feed-forward block
  ln_rows<<<dim3(8192), dim3(256), 0, stream>>>(X1, ff_ng, ff_nb, XN);
  gemmP(XN, ffw1T, nullptr, nullptr, 1, Hb, 1, 8192, 4096, 1024);     // ff1
  gemmP(Hb, ffw2T, nullptr, X1, 0, d_out, 0, 8192, 1024, 4096);       // ff2
}

// Round 2
// 651.182 us; speedup vs baseline: 1.0491x; 1.0491x over previous
//
#include <hip/hip_runtime.h>
#include <hip/hip_bf16.h>
#include <stdint.h>

#define DEV static __device__ __forceinline__

// Problem constants
constexpr int kB = 2, kT = 16, kL = 256, kM = 512;
constexpr int kD = 1024, kH = 16, kDH = 64, kHT = 8, kROT = 32;
constexpr int kN = kT * kL;  // 4096 flattened seq for cross-attn
constexpr float kEPS = 1e-5f;
constexpr float kNEG = -1.0e9f;
constexpr float kSCALE = 0.125f;  // 1/sqrt(64)

typedef __attribute__((ext_vector_type(8))) short short8;   // 8 bf16 (guide §3)
typedef __attribute__((ext_vector_type(4))) float floatx4;
typedef __attribute__((ext_vector_type(16))) float floatx16;

DEV float b2f(__hip_bfloat16 v) { return __bfloat162float(v); }
DEV __hip_bfloat16 f2b(float v) { return __float2bfloat16(v); }
DEV float s2f(short x) {
  __hip_bfloat16_raw r; r.x = (unsigned short)x;
  return __bfloat162float(__hip_bfloat16(r));
}

// async global->LDS, 16B per lane; LDS dst = wave-uniform base + lane*16
DEV void gl2lds16(const __hip_bfloat16* g, __hip_bfloat16* l) {
  __builtin_amdgcn_global_load_lds(
      (const __attribute__((address_space(1))) void*)g,
      (__attribute__((address_space(3))) void*)l, 16, 0, 0);
}

// ---------------- fused transposes + mask conversion ----------------
struct TransArgs {
  const float* src[7];
  __hip_bfloat16* dst[7];
  const unsigned char* cmraw;
  const unsigned char* amraw;
  int* cmask;
  int* amask;
};
__constant__ const int kTKd[7] = {1024, 1024, 1024, 1024, 512, 1024, 4096};
__constant__ const int kTNd[7] = {1024, 2048, 1024, 1536, 1024, 4096, 1024};
__constant__ const int kTCum[8] = {0, 1024, 3072, 4096, 5632, 6144, 10240, 14336};

DEV int mask_val(const unsigned char* raw, int i) {
  unsigned char b1 = raw[1], b3 = raw[3];
  if (b1 == 0x3F) return ((const unsigned short*)raw)[i] != 0;       // bf16
  if (b3 == 0x3F) return ((const float*)raw)[i] != 0.0f;             // fp32
  if (b1 == 1)    return raw[i] != 0;                                // bool
  return ((const int*)raw)[i] != 0;                                  // int32
}

__global__ __launch_bounds__(256) void transpose_all(TransArgs a) {
  int id = blockIdx.x;
  if (id >= 14336) {  // mask blocks
    if (id == 14336) {
      for (int i = threadIdx.x; i < kB * kM; i += 256)
        a.cmask[i] = mask_val(a.cmraw, i);
    } else {
      if (threadIdx.x < kB * kT)
        a.amask[threadIdx.x] = mask_val(a.amraw, threadIdx.x);
    }
    return;
  }
  int seg = 0;
  #pragma unroll
  for (int s = 1; s < 7; s++) seg += (id >= kTCum[s]);
  unsigned t = id - kTCum[seg];
  int Kd = kTKd[seg], Nd = kTNd[seg];
  unsigned ntx = Nd / 32;
  int n0 = (t % ntx) * 32, k0 = (t / ntx) * 32;
  const float* W = a.src[seg];
  __hip_bfloat16* Wt = a.dst[seg];
  __shared__ float tile[32][33];
  int tx = threadIdx.x & 31, ty = threadIdx.x >> 5;
  for (int i = 0; i < 32; i += 8)
    tile[ty + i][tx] = W[(size_t)(k0 + ty + i) * Nd + n0 + tx];
  __syncthreads();
  for (int i = 0; i < 32; i += 8)
    Wt[(size_t)(n0 + ty + i) * Kd + k0 + tx] = f2b(tile[tx][ty + i]);
}

// ---------------- LayerNorm over D=1024 fp32 in, bf16 out; 1 block/row -----
DEV void ln_body(const float* xr, const float* g, const float* bb,
                 __hip_bfloat16* outr, int tid) {
  float4 xv = *(const float4*)(xr + tid * 4);
  float s = xv.x + xv.y + xv.z + xv.w;
  float s2 = xv.x * xv.x + xv.y * xv.y + xv.z * xv.z + xv.w * xv.w;
  for (int off = 32; off; off >>= 1) {
    s += __shfl_down(s, off);
    s2 += __shfl_down(s2, off);
  }
  __shared__ float rs[4], rs2[4];
  if ((tid & 63) == 0) { rs[tid >> 6] = s; rs2[tid >> 6] = s2; }
  __syncthreads();
  float ts = rs[0] + rs[1] + rs[2] + rs[3];
  float ts2 = rs2[0] + rs2[1] + rs2[2] + rs2[3];
  float mu = ts * (1.f / kD);
  float var = ts2 * (1.f / kD) - mu * mu;
  float rstd = rsqrtf(var + kEPS);
  float4 gv = *(const float4*)(g + tid * 4);
  float4 bv = *(const float4*)(bb + tid * 4);
  ushort4 o;
  o.x = __hip_bfloat16_raw(f2b((xv.x - mu) * rstd * gv.x + bv.x)).x;
  o.y = __hip_bfloat16_raw(f2b((xv.y - mu) * rstd * gv.y + bv.y)).x;
  o.z = __hip_bfloat16_raw(f2b((xv.z - mu) * rstd * gv.z + bv.z)).x;
  o.w = __hip_bfloat16_raw(f2b((xv.w - mu) * rstd * gv.w + bv.w)).x;
  *(ushort4*)(outr + tid * 4) = o;
}

__global__ __launch_bounds__(256) void ln_rows(
    const float* __restrict__ X, const float* __restrict__ g,
    const float* __restrict__ bb, __hip_bfloat16* __restrict__ out) {
  int row = blockIdx.x;
  ln_body(X + (size_t)row * kD, g, bb, out + (size_t)row * kD, threadIdx.x);
}

// fused LN over x (8192 rows) and ctx (1024 rows)
__global__ __launch_bounds__(256) void ln_rows2(
    const float* __restrict__ X, const float* __restrict__ g,
    const float* __restrict__ bb, __hip_bfloat16* __restrict__ out,
    const float* __restrict__ X2, const float* __restrict__ g2,
    const float* __restrict__ bb2, __hip_bfloat16* __restrict__ out2) {
  int row = blockIdx.x;
  if (row < 8192)
    ln_body(X + (size_t)row * kD, g, bb, out + (size_t)row * kD, threadIdx.x);
  else {
    int r = row - 8192;
    ln_body(X2 + (size_t)r * kD, g2, bb2, out2 + (size_t)r * kD, threadIdx.x);
  }
}

// ---------------- legacy MFMA GEMM core: 128x128 tile, BK=64 ---------------
// Proven m97-class structure (baseline 640.9us). Used for all N=1024 shapes
// (their 256^2 grids would be 128 blocks = half the chip idle at 1 block/CU).
DEV void gemm_body(__hip_bfloat16* As, __hip_bfloat16* Bs,
                   const __hip_bfloat16* A, const __hip_bfloat16* Bt,
                   const float* bias, const float* res, int gelu,
                   void* out, int outBf16, int Nd, int Kd, int m0, int n0) {
  int tid = threadIdx.x, wave = tid >> 6, lane = tid & 63;
  int l32 = lane & 31, kg = lane >> 5;
  int wm = (wave >> 1) * 64, wn = (wave & 1) * 64;

  int srow = wave * 32 + (lane >> 3);
  int schunk8 = (((lane & 7) ^ ((lane >> 3) & 7)) << 3);
  const __hip_bfloat16* Ag = A + (size_t)(m0 + srow) * Kd + schunk8;
  const __hip_bfloat16* Bg = Bt + (size_t)(n0 + srow) * Kd + schunk8;
  __hip_bfloat16* Al = As + wave * 32 * 64;
  __hip_bfloat16* Bl = Bs + wave * 32 * 64;

  floatx16 acc[2][2] = {};
  for (int k0 = 0; k0 < Kd; k0 += 64) {
    #pragma unroll
    for (int i = 0; i < 4; i++) {
      gl2lds16(Ag + (size_t)(i * 8) * Kd + k0, Al + i * 512);
      gl2lds16(Bg + (size_t)(i * 8) * Kd + k0, Bl + i * 512);
    }
    __syncthreads();
    #pragma unroll
    for (int ks = 0; ks < 4; ks++) {
      int c = ks * 2 + kg;
      short8 af[2], bf2[2];
      #pragma unroll
      for (int fa = 0; fa < 2; fa++) {
        int row = wm + fa * 32 + l32;
        af[fa] = *(const short8*)(&As[row * 64 + (c ^ (row & 7)) * 8]);
      }
      #pragma unroll
      for (int fb = 0; fb < 2; fb++) {
        int row = wn + fb * 32 + l32;
        bf2[fb] = *(const short8*)(&Bs[row * 64 + (c ^ (row & 7)) * 8]);
      }
      #pragma unroll
      for (int fa = 0; fa < 2; fa++)
        #pragma unroll
        for (int fb = 0; fb < 2; fb++)
          acc[fa][fb] = __builtin_amdgcn_mfma_f32_32x32x16_bf16(
              af[fa], bf2[fb], acc[fa][fb], 0, 0, 0);
    }
    __syncthreads();
  }
  // epilogue
  #pragma unroll
  for (int fa = 0; fa < 2; fa++) {
    #pragma unroll
    for (int fb = 0; fb < 2; fb++) {
      int col = n0 + wn + fb * 32 + l32;
      float bv = bias ? bias[col] : 0.f;
      #pragma unroll
      for (int r = 0; r < 16; r++) {
        int row = m0 + wm + fa * 32 + (r & 3) + 8 * (r >> 2) + 4 * kg;
        float v = acc[fa][fb][r] + bv;
        if (gelu) {  // gelu(x) ~= x * sigmoid(1.702 x)
          v = v * (1.f / (1.f + __expf(-1.702f * v)));
        }
        size_t o = (size_t)row * Nd + col;
        if (res) v += res[o];
        if (outBf16) ((__hip_bfloat16*)out)[o] = f2b(v);
        else         ((float*)out)[o] = v;
      }
    }
  }
}

__global__ __launch_bounds__(256) void gemm_bf16(
    const __hip_bfloat16* __restrict__ A, const __hip_bfloat16* __restrict__ Bt,
    const float* __restrict__ bias, const float* __restrict__ res, int gelu,
    void* __restrict__ out, int outBf16, int Nd, int Kd) {
  __shared__ __align__(16) __hip_bfloat16 As[128 * 64];  // 16 KB
  __shared__ __align__(16) __hip_bfloat16 Bs[128 * 64];  // 16 KB
  gemm_body(As, Bs, A, Bt, bias, res, gelu, out, outBf16, Nd, Kd,
            blockIdx.x * 128, blockIdx.y * 128);
}

// grouped q-proj (512 blocks: 64x8) + kv-proj (128 blocks: 8x16), 1-D grid 640
__global__ __launch_bounds__(256) void gemm_pair(
    const __hip_bfloat16* __restrict__ A0, const __hip_bfloat16* __restrict__ B0,
    void* __restrict__ o0,
    const __hip_bfloat16* __restrict__ A1, const __hip_bfloat16* __restrict__ B1,
    void* __restrict__ o1) {
  __shared__ __align__(16) __hip_bfloat16 As[128 * 64];
  __shared__ __align__(16) __hip_bfloat16 Bs[128 * 64];
  int id = blockIdx.x;
  if (id < 512) {  // q: M=8192 N=1024 K=1024
    gemm_body(As, Bs, A0, B0, nullptr, nullptr, 0, o0, 1, 1024, 1024,
              (id & 63) * 128, (id >> 6) * 128);
  } else {         // kv: M=1024 N=2048 K=1024
    int r = id - 512;
    gemm_body(As, Bs, A1, B1, nullptr, nullptr, 0, o1, 1, 2048, 1024,
              (r & 7) * 128, (r >> 3) * 128);
  }
}

// ---------------- 8-phase 256x256 MFMA GEMM (m201-style port) --------------
// BM=BN=256, BK=64, 8 waves (2M x 4N), per-wave 128x64 out via 32x32x16 MFMA.
// 8 phases per iteration of 2 K-tiles (ta=2i buf0, tb=2i+1 buf1):
//   phase = { ds_reads (one-phase-ahead A-frag; B once per K-tile)
//             | stage 1 half-tile (2x global_load_lds)
//             | s_barrier; lgkmcnt(0); sched_barrier
//             | setprio(1); 8 MFMA; setprio(0)
//             | [counted vmcnt before closing barrier at P3/P7]
//             | s_barrier }
// Read schedule (phase -> reads):
//   P1: B(ta)[8]+A1(ta)  P2: A2(ta)  P3: A3(ta)  P4: A0(tb)
//   P5: B(tb)[8]+A1(tb)  P6: A2(tb)  P7: A3(tb)  P8: A0(ta+2)
// MFMA at phase p uses A-frag read at p-1 (ping-pong aA/aB), B read in-tile.
// Stage schedule (half-tiles; deadline-checked, region-free-checked):
//   P1: buf1.A.h1(tb)   P2: buf0.B.h0(ta+2)  P3: buf0.B.h1(ta+2)
//   P4: buf0.A.h0(ta+2) P5: buf0.A.h1(ta+2)  P6: buf1.B.h0(tb+2)
//   P7: buf1.B.h1(tb+2) P8: buf1.A.h0(tb+2)
// Gates (vmcnt BEFORE a barrier so the guarantee is workgroup-wide):
//   end-P3: vmcnt(4) completes stages <= P1 (tile tb fully landed; newest 4 =
//           P2,P3 stay in flight).  end-P7: vmcnt(4) completes <= P5 (tile
//           ta+2 landed; newest 4 = P6,P7 in flight).  Last iteration: P3
//           gate is vmcnt(0) (drain), P7 gate skipped (no next tile).
// Swizzle: rows of 64 bf16 = 8 chunks of 16B; phys = chunk ^ (row&7), applied
// on BOTH sides (pre-swizzled global source at stage + XOR on ds_read).
__global__ __launch_bounds__(512, 2) void gemm_8p(
    const __hip_bfloat16* __restrict__ A, const __hip_bfloat16* __restrict__ Bt,
    const float* __restrict__ bias, const float* __restrict__ res, int gelu,
    void* __restrict__ out, int outBf16, int Nd, int Kd) {
  __shared__ __align__(16) __hip_bfloat16 As[2][256][64];  // 64 KB
  __shared__ __align__(16) __hip_bfloat16 Bs[2][256][64];  // 64 KB
  const int m0 = blockIdx.x * 256, n0 = blockIdx.y * 256;
  const int tid = threadIdx.x, wave = tid >> 6, lane = tid & 63;
  const int l32 = lane & 31, kg = lane >> 5;
  const int wm = (wave >> 2) * 128;   // M half (2 waves)
  const int wn = (wave & 3) * 64;     // N quarter (4 waves)
  const int NT = Kd >> 6;             // K-tiles of 64 (Kd multiple of 128)
  const int NI = NT >> 1;             // iterations (2 K-tiles each)

  // staging: per half-tile (128 rows x 64 cols = 16KB) each thread issues 2
  // gl2lds16; wave w covers rows w*8..w*8+7 (+64 for the 2nd load).
  const int srow = (wave << 3) + (lane >> 3);                  // 0..63
  const int swz8 = (((lane & 7) ^ ((lane >> 3) & 7)) << 3);    // source swizzle
  const __hip_bfloat16* Agt = A + (size_t)(m0 + srow) * Kd + swz8;
  const __hip_bfloat16* Bgt = Bt + (size_t)(n0 + srow) * Kd + swz8;

  auto stA = [&](int buf, int hf, int t) {
    const __hip_bfloat16* g = Agt + (size_t)(hf * 128) * Kd + t * 64;
    __hip_bfloat16* l = &As[buf][hf * 128 + (wave << 3)][0];
    gl2lds16(g, l);
    gl2lds16(g + (size_t)64 * Kd, l + 64 * 64);
  };
  auto stB = [&](int buf, int hf, int t) {
    const __hip_bfloat16* g = Bgt + (size_t)(hf * 128) * Kd + t * 64;
    __hip_bfloat16* l = &Bs[buf][hf * 128 + (wave << 3)][0];
    gl2lds16(g, l);
    gl2lds16(g + (size_t)64 * Kd, l + 64 * 64);
  };
  auto ldA4 = [&](int buf, int mf, short8* d) {   // A-frags, one M-frag x 4 ks
    int row = wm + mf * 32 + l32;
    const __hip_bfloat16* p = &As[buf][row][0];
    #pragma unroll
    for (int ks = 0; ks < 4; ks++) {
      int c = ks * 2 + kg;
      d[ks] = *(const short8*)(p + ((c ^ (row & 7)) << 3));
    }
  };
  auto ldB8 = [&](int buf, short8* d) {           // B-frags, 2 N-frags x 4 ks
    #pragma unroll
    for (int fb = 0; fb < 2; fb++) {
      int row = wn + fb * 32 + l32;
      const __hip_bfloat16* p = &Bs[buf][row][0];
      #pragma unroll
      for (int ks = 0; ks < 4; ks++) {
        int c = ks * 2 + kg;
        d[fb * 4 + ks] = *(const short8*)(p + ((c ^ (row & 7)) << 3));
      }
    }
  };

  floatx16 acc[4][2] = {};
  auto phase_mid = [&] {
    asm volatile("" ::: "memory");
    __builtin_amdgcn_s_barrier();
    asm volatile("s_waitcnt lgkmcnt(0)" ::: "memory");
    __builtin_amdgcn_sched_barrier(0);
  };
  auto phase_end = [&] {
    asm volatile("" ::: "memory");
    __builtin_amdgcn_s_barrier();
    asm volatile("" ::: "memory");
  };

  short8 aA[4], aB[4], b[8];

  #define MMAQ(mf, ar)                                                      \
    __builtin_amdgcn_s_setprio(1);                                          \
    _Pragma("unroll")                                                       \
    for (int ks = 0; ks < 4; ks++) {                                        \
      acc[mf][0] = __builtin_amdgcn_mfma_f32_32x32x16_bf16(                 \
          ar[ks], b[ks], acc[mf][0], 0, 0, 0);                              \
      acc[mf][1] = __builtin_amdgcn_mfma_f32_32x32x16_bf16(                 \
          ar[ks], b[4 + ks], acc[mf][1], 0, 0, 0);                          \
    }                                                                       \
    __builtin_amdgcn_s_setprio(0);

  // ---- prologue: buf0 <- tile 0 (8 loads), buf1 <- tile 1 partial (6) ----
  stB(0, 0, 0); stB(0, 1, 0); stA(0, 0, 0); stA(0, 1, 0);
  stB(1, 0, 1); stB(1, 1, 1); stA(1, 0, 1);
  asm volatile("s_waitcnt vmcnt(6)" ::: "memory");
  __builtin_amdgcn_s_barrier();
  asm volatile("" ::: "memory");
  ldA4(0, 0, aA);               // A0(t0); drained by P1's lgkmcnt(0)

  for (int i = 0; i < NI; ++i) {
    const int ta = 2 * i, tb = ta + 1;
    const bool more = (i + 1 < NI);
    // ---- P1: reads B(ta)+A1(ta); stage buf1.A.h1(tb); MFMA Q0(ta) [aA]
    ldB8(0, b);
    ldA4(0, 1, aB);
    stA(1, 1, tb);
    phase_mid();
    MMAQ(0, aA);
    phase_end();
    // ---- P2: reads A2(ta); stage buf0.B.h0(ta+2); MFMA Q1(ta) [aB]
    ldA4(0, 2, aA);
    if (more) stB(0, 0, ta + 2);
    phase_mid();
    MMAQ(1, aB);
    phase_end();
    // ---- P3: reads A3(ta); stage buf0.B.h1(ta+2); MFMA Q2(ta) [aA]; GATE
    ldA4(0, 3, aB);
    if (more) stB(0, 1, ta + 2);
    phase_mid();
    MMAQ(2, aA);
    if (more) asm volatile("s_waitcnt vmcnt(4)" ::: "memory");
    else      asm volatile("s_waitcnt vmcnt(0)" ::: "memory");
    phase_end();                 // after this barrier, tile tb fully in LDS
    // ---- P4: reads A0(tb); stage buf0.A.h0(ta+2); MFMA Q3(ta) [aB]
    ldA4(1, 0, aA);
    if (more) stA(0, 0, ta + 2);
    phase_mid();
    MMAQ(3, aB);
    phase_end();
    // ---- P5: reads B(tb)+A1(tb); stage buf0.A.h1(ta+2); MFMA Q0(tb) [aA]
    ldB8(1, b);
    ldA4(1, 1, aB);
    if (more) stA(0, 1, ta + 2);
    phase_mid();
    MMAQ(0, aA);
    phase_end();
    // ---- P6: reads A2(tb); stage buf1.B.h0(tb+2); MFMA Q1(tb) [aB]
    ldA4(1, 2, aA);
    if (more) stB(1, 0, tb + 2);
    phase_mid();
    MMAQ(1, aB);
    phase_end();
    // ---- P7: reads A3(tb); stage buf1.B.h1(tb+2); MFMA Q2(tb) [aA]; GATE
    ldA4(1, 3, aB);
    if (more) stB(1, 1, tb + 2);
    phase_mid();
    MMAQ(2, aA);
    if (more) asm volatile("s_waitcnt vmcnt(4)" ::: "memory");
    phase_end();                 // after this barrier, tile ta+2 fully in LDS
    // ---- P8: reads A0(ta+2); stage buf1.A.h0(tb+2); MFMA Q3(tb) [aB]
    if (more) {
      ldA4(0, 0, aA);
      stA(1, 0, tb + 2);
    }
    phase_mid();
    MMAQ(3, aB);
    phase_end();
  }
  #undef MMAQ

  // epilogue (32x32 C/D frag map: row=(r&3)+8*(r>>2)+4*kg, col=l32)
  #pragma unroll
  for (int mf = 0; mf < 4; mf++) {
    #pragma unroll
    for (int fb = 0; fb < 2; fb++) {
      int col = n0 + wn + fb * 32 + l32;
      float bv = bias ? bias[col] : 0.f;
      #pragma unroll
      for (int r = 0; r < 16; r++) {
        int row = m0 + wm + mf * 32 + (r & 3) + 8 * (r >> 2) + 4 * kg;
        float v = acc[mf][fb][r] + bv;
        if (gelu) v = v * (1.f / (1.f + __expf(-1.702f * v)));
        size_t o = (size_t)row * Nd + col;
        if (res) v += res[o];
        if (outBf16) ((__hip_bfloat16*)out)[o] = f2b(v);
        else         ((float*)out)[o] = v;
      }
    }
  }
}

// ---------------- MFMA cross-attention (flash-style online softmax) --------
__global__ __launch_bounds__(256) void cross_attn_mfma(
    const __hip_bfloat16* __restrict__ Qb,   // [B*N][1024]
    const __hip_bfloat16* __restrict__ KVb,  // [B*M][2048] (k | v)
    const int* __restrict__ cmask,           // [B*M]
    __hip_bfloat16* __restrict__ Ob) {       // [B*N][1024]
  __shared__ __align__(16) __hip_bfloat16 Vbf[2][8][64][8];   // 16 KB
  __shared__ __align__(16) __hip_bfloat16 Paf[4][8][16][8];   // 8 KB
  int b = blockIdx.y >> 4, h = blockIdx.y & 15;
  int q0 = blockIdx.x * 64;
  int tid = threadIdx.x, wave = tid >> 6, lane = tid & 63;
  int l16 = lane & 15, quad = lane >> 4;

  const __hip_bfloat16* qrow =
      Qb + (size_t)(b * kN + q0 + wave * 16 + l16) * 1024 + h * 64 + quad * 8;
  short8 qf0 = *(const short8*)qrow;
  short8 qf1 = *(const short8*)(qrow + 32);

  floatx4 of[4] = {};
  float Mr[4] = {-1e30f, -1e30f, -1e30f, -1e30f};
  float Lr[4] = {};

  int skey = tid >> 2, sd0 = (tid & 3) * 16;

  for (int kt = 0; kt < 8; kt++) {
    int buf = kt & 1;
    {
      const __hip_bfloat16* src =
          KVb + (size_t)(b * kM + kt * 64 + skey) * 2048 + 1024 + h * 64 + sd0;
      short8 v0 = *(const short8*)src;
      short8 v1 = *(const short8*)(src + 8);
      int kb = skey >> 3, kj = skey & 7;
      #pragma unroll
      for (int j = 0; j < 8; j++) {
        Vbf[buf][kb][sd0 + j][kj] = __hip_bfloat16(__hip_bfloat16_raw{(unsigned short)v0[j]});
        Vbf[buf][kb][sd0 + 8 + j][kj] = __hip_bfloat16(__hip_bfloat16_raw{(unsigned short)v1[j]});
      }
    }
    __syncthreads();

    floatx4 sf[4];
    #pragma unroll
    for (int nf = 0; nf < 4; nf++) {
      const __hip_bfloat16* krow =
          KVb + (size_t)(b * kM + kt * 64 + nf * 16 + l16) * 2048 + h * 64 + quad * 8;
      short8 kf0 = *(const short8*)krow;
      short8 kf1 = *(const short8*)(krow + 32);
      floatx4 z = {};
      z = __builtin_amdgcn_mfma_f32_16x16x32_bf16(qf0, kf0, z, 0, 0, 0);
      z = __builtin_amdgcn_mfma_f32_16x16x32_bf16(qf1, kf1, z, 0, 0, 0);
      sf[nf] = z;
    }

    float sv[4][4];
    #pragma unroll
    for (int nf = 0; nf < 4; nf++) {
      int mk = cmask[b * kM + kt * 64 + nf * 16 + l16];
      #pragma unroll
      for (int r = 0; r < 4; r++)
        sv[nf][r] = mk ? sf[nf][r] * kSCALE : kNEG;
    }
    float mx[4];
    #pragma unroll
    for (int r = 0; r < 4; r++) {
      float m = fmaxf(fmaxf(sv[0][r], sv[1][r]), fmaxf(sv[2][r], sv[3][r]));
      #pragma unroll
      for (int off = 1; off < 16; off <<= 1) m = fmaxf(m, __shfl_xor(m, off));
      mx[r] = m;
    }
    float alpha[4], Mn[4];
    #pragma unroll
    for (int r = 0; r < 4; r++) {
      Mn[r] = fmaxf(Mr[r], mx[r]);
      alpha[r] = __expf(Mr[r] - Mn[r]);
      Mr[r] = Mn[r];
    }
    float p[4][4];
    float rsum[4];
    #pragma unroll
    for (int r = 0; r < 4; r++) {
      float s = 0.f;
      #pragma unroll
      for (int nf = 0; nf < 4; nf++) {
        float e = __expf(sv[nf][r] - Mn[r]);
        p[nf][r] = e; s += e;
      }
      #pragma unroll
      for (int off = 1; off < 16; off <<= 1) s += __shfl_xor(s, off);
      rsum[r] = s;
    }
    #pragma unroll
    for (int r = 0; r < 4; r++) Lr[r] = Lr[r] * alpha[r] + rsum[r];
    #pragma unroll
    for (int df = 0; df < 4; df++)
      #pragma unroll
      for (int r = 0; r < 4; r++) of[df][r] *= alpha[r];

    #pragma unroll
    for (int nf = 0; nf < 4; nf++) {
      int col = nf * 16 + l16;
      int kb = col >> 3, kj = col & 7;
      #pragma unroll
      for (int r = 0; r < 4; r++)
        Paf[wave][kb][quad * 4 + r][kj] = f2b(p[nf][r]);
    }
    __builtin_amdgcn_s_waitcnt(0);

    short8 pf0 = *(const short8*)(&Paf[wave][quad][l16][0]);
    short8 pf1 = *(const short8*)(&Paf[wave][quad + 4][l16][0]);
    #pragma unroll
    for (int df = 0; df < 4; df++) {
      short8 vf0 = *(const short8*)(&Vbf[buf][quad][df * 16 + l16][0]);
      short8 vf1 = *(const short8*)(&Vbf[buf][quad + 4][df * 16 + l16][0]);
      of[df] = __builtin_amdgcn_mfma_f32_16x16x32_bf16(pf0, vf0, of[df], 0, 0, 0);
      of[df] = __builtin_amdgcn_mfma_f32_16x16x32_bf16(pf1, vf1, of[df], 0, 0, 0);
    }
  }

  #pragma unroll
  for (int df = 0; df < 4; df++) {
    #pragma unroll
    for (int r = 0; r < 4; r++) {
      int row = q0 + wave * 16 + quad * 4 + r;
      float v = of[df][r] / Lr[r];
      Ob[(size_t)(b * kN + row) * 1024 + h * 64 + df * 16 + l16] = f2b(v);
    }
  }
}

// ---------------- temporal attention (with RoPE) ----------------
__global__ __launch_bounds__(64) void temporal_attn(
    const __hip_bfloat16* __restrict__ QKVb,  // [B*T*L][1536] (q|k|v)
    const float* __restrict__ rope,           // [T][32] fp32
    const int* __restrict__ amask,            // [B*T]
    __hip_bfloat16* __restrict__ Otb) {       // [B*T*L][512]
  __shared__ float qs[16][65], ks[16][65], vs[16][65];
  __shared__ float Ps[16][17];
  int idx = blockIdx.x;
  int h = idx & 7, l = (idx >> 3) & 255, b = idx >> 11;
  int lane = threadIdx.x;

  {  // vectorized loads: 6x short8 per thread (16B each)
    int tr = lane >> 2, c0 = (lane & 3) * 16;
    const __hip_bfloat16* base =
        QKVb + ((size_t)(b * kT + tr) * kL + l) * 1536 + h * 64;
    short8 qa = *(const short8*)(base + c0);
    short8 qb = *(const short8*)(base + c0 + 8);
    short8 ka = *(const short8*)(base + 512 + c0);
    short8 kb = *(const short8*)(base + 512 + c0 + 8);
    short8 va = *(const short8*)(base + 1024 + c0);
    short8 vb = *(const short8*)(base + 1024 + c0 + 8);
    #pragma unroll
    for (int j = 0; j < 8; j++) {
      qs[tr][c0 + j] = s2f(qa[j]) * kSCALE;
      qs[tr][c0 + 8 + j] = s2f(qb[j]) * kSCALE;
      ks[tr][c0 + j] = s2f(ka[j]);
      ks[tr][c0 + 8 + j] = s2f(kb[j]);
      vs[tr][c0 + j] = s2f(va[j]);
      vs[tr][c0 + 8 + j] = s2f(vb[j]);
    }
  }
  __syncthreads();
  {
    int rt = lane >> 2, rd0 = (lane & 3) * 8;
    float nq[8], nk[8];
    for (int j = 0; j < 8; j++) {
      int d = rd0 + j;
      float ang = rope[rt * kROT + d];
      float cv = cosf(ang), sv = sinf(ang);
      float oq = (d < 16) ? -qs[rt][d + 16] : qs[rt][d - 16];
      float ok = (d < 16) ? -ks[rt][d + 16] : ks[rt][d - 16];
      nq[j] = qs[rt][d] * cv + oq * sv;
      nk[j] = ks[rt][d] * cv + ok * sv;
    }
    __syncthreads();
    for (int j = 0; j < 8; j++) { qs[rt][rd0 + j] = nq[j]; ks[rt][rd0 + j] = nk[j]; }
  }
  __syncthreads();
  {
    int tq = lane >> 2, tk0 = (lane & 3) * 4;
    float s[4] = {0, 0, 0, 0};
    for (int d = 0; d < 64; d++) {
      float qv = qs[tq][d];
      s[0] += qv * ks[tk0 + 0][d];
      s[1] += qv * ks[tk0 + 1][d];
      s[2] += qv * ks[tk0 + 2][d];
      s[3] += qv * ks[tk0 + 3][d];
    }
    for (int jj = 0; jj < 4; jj++)
      Ps[tq][tk0 + jj] = amask[b * kT + tk0 + jj] ? s[jj] : kNEG;
  }
  __syncthreads();
  if (lane < 16) {
    float mx = -1e30f;
    for (int k = 0; k < 16; k++) mx = fmaxf(mx, Ps[lane][k]);
    float sum = 0.f;
    for (int k = 0; k < 16; k++) { float p = __expf(Ps[lane][k] - mx); Ps[lane][k] = p; sum += p; }
    float inv = 1.f / sum;
    for (int k = 0; k < 16; k++) Ps[lane][k] *= inv;
  }
  __syncthreads();
  for (int tq = 0; tq < 16; tq++) {
    float acc = 0.f;
    for (int tk = 0; tk < 16; tk++) acc += Ps[tq][tk] * vs[tk][lane];
    float qm = amask[b * kT + tq] ? 1.f : 0.f;
    Otb[((size_t)(b * kT + tq) * kL + l) * 512 + h * 64 + lane] = f2b(acc * qm);
  }
}

// ---------------- launcher ----------------
extern "C" void kernel_launch(void* const* d_in, const int* in_sizes, int n_in,
                              void* d_out, int out_size, void* d_ws, size_t ws_size,
                              hipStream_t stream) {
  const float* x       = (const float*)d_in[0];
  const float* ctx     = (const float*)d_in[1];
  const float* rope    = (const float*)d_in[2];
  const float* ca_ng   = (const float*)d_in[3];
  const float* ca_nb   = (const float*)d_in[4];
  const float* ca_cng  = (const float*)d_in[5];
  const float* ca_cnb  = (const float*)d_in[6];
  const float* ca_wq   = (const float*)d_in[7];
  const float* ca_wkv  = (const float*)d_in[8];
  const float* ca_wo   = (const float*)d_in[9];
  const float* ta_ng   = (const float*)d_in[10];
  const float* ta_nb   = (const float*)d_in[11];
  const float* ta_wqkv = (const float*)d_in[12];
  const float* ta_bqkv = (const float*)d_in[13];
  const float* ta_wo   = (const float*)d_in[14];
  const float* ff_ng   = (const float*)d_in[15];
  const float* ff_nb   = (const float*)d_in[16];
  const float* ff_w1   = (const float*)d_in[17];
  const float* ff_w2   = (const float*)d_in[18];
  const unsigned char* cmraw = (const unsigned char*)d_in[19];
  const unsigned char* amraw = (const unsigned char*)d_in[20];

  char* wsc = (char*)d_ws;
  size_t off = 0;
  auto take = [&](size_t bytes) {
    char* p = wsc + off;
    off = (off + bytes + 255) & ~(size_t)255;
    return p;
  };
  __hip_bfloat16* wqT   = (__hip_bfloat16*)take((size_t)1024 * 1024 * 2);
  __hip_bfloat16* wkvT  = (__hip_bfloat16*)take((size_t)2048 * 1024 * 2);
  __hip_bfloat16* woT   = (__hip_bfloat16*)take((size_t)1024 * 1024 * 2);
  __hip_bfloat16* wqkvT = (__hip_bfloat16*)take((size_t)1536 * 1024 * 2);
  __hip_bfloat16* tawoT = (__hip_bfloat16*)take((size_t)1024 * 512 * 2);
  __hip_bfloat16* ffw1T = (__hip_bfloat16*)take((size_t)4096 * 1024 * 2);
  __hip_bfloat16* ffw2T = (__hip_bfloat16*)take((size_t)1024 * 4096 * 2);
  __hip_bfloat16* XN  = (__hip_bfloat16*)take((size_t)8192 * 1024 * 2);
  __hip_bfloat16* CN  = (__hip_bfloat16*)take((size_t)1024 * 1024 * 2);
  __hip_bfloat16* Qb  = (__hip_bfloat16*)take((size_t)8192 * 1024 * 2);
  __hip_bfloat16* KVb = (__hip_bfloat16*)take((size_t)1024 * 2048 * 2);
  __hip_bfloat16* Ob  = (__hip_bfloat16*)take((size_t)8192 * 1024 * 2);
  float*          X1  = (float*)take((size_t)8192 * 1024 * 4);
  __hip_bfloat16* Hb  = (__hip_bfloat16*)take((size_t)8192 * 4096 * 2);
  int* cmask = (int*)take((size_t)kB * kM * 4);
  int* amask = (int*)take((size_t)kB * kT * 4);
  if (off > ws_size) return;

  __hip_bfloat16* QKVb = Hb;  // [8192][1536], dead before Hb is written
  __hip_bfloat16* OTb  = Qb;  // [8192][512], Q dead after cross_attn

  auto gemm = [&](const __hip_bfloat16* A, const __hip_bfloat16* Bt,
                  const float* bias, const float* res, int gelu, void* out,
                  int outBf16, int Md, int Nd, int Kd) {
    gemm_bf16<<<dim3(Md / 128, Nd / 128), dim3(256), 0, stream>>>(
        A, Bt, bias, res, gelu, out, outBf16, Nd, Kd);
  };
  auto gemm8 = [&](const __hip_bfloat16* A, const __hip_bfloat16* Bt,
                   const float* bias, const float* res, int gelu, void* out,
                   int outBf16, int Md, int Nd, int Kd) {
    gemm_8p<<<dim3(Md / 256, Nd / 256), dim3(512), 0, stream>>>(
        A, Bt, bias, res, gelu, out, outBf16, Nd, Kd);
  };

  // fused transposes + masks (1 launch)
  TransArgs ta;
  ta.src[0] = ca_wq;   ta.dst[0] = wqT;
  ta.src[1] = ca_wkv;  ta.dst[1] = wkvT;
  ta.src[2] = ca_wo;   ta.dst[2] = woT;
  ta.src[3] = ta_wqkv; ta.dst[3] = wqkvT;
  ta.src[4] = ta_wo;   ta.dst[4] = tawoT;
  ta.src[5] = ff_w1;   ta.dst[5] = ffw1T;
  ta.src[6] = ff_w2;   ta.dst[6] = ffw2T;
  ta.cmraw = cmraw; ta.amraw = amraw; ta.cmask = cmask; ta.amask = amask;
  transpose_all<<<dim3(14338), dim3(256), 0, stream>>>(ta);

  // cross-attention block
  ln_rows2<<<dim3(9216), dim3(256), 0, stream>>>(x, ca_ng, ca_nb, XN,
                                                 ctx, ca_cng, ca_cnb, CN);
  gemm_pair<<<dim3(640), dim3(256), 0, stream>>>(XN, wqT, Qb, CN, wkvT, KVb);
  cross_attn_mfma<<<dim3(kN / 64, kB * kH), dim3(256), 0, stream>>>(Qb, KVb, cmask, Ob);
  gemm(Ob, woT, nullptr, x, 0, X1, 0, 8192, 1024, 1024);

  // temporal attention block
  ln_rows<<<dim3(8192), dim3(256), 0, stream>>>(X1, ta_ng, ta_nb, XN);
  gemm8(XN, wqkvT, ta_bqkv, nullptr, 0, QKVb, 1, 8192, 1536, 1024);
  temporal_attn<<<dim3(kB * kL * kHT), dim3(64), 0, stream>>>(QKVb, rope, amask, OTb);
  gemm(OTb, tawoT, nullptr, X1, 0, X1, 0, 8192, 1024, 512);

  // feed-forward block
  ln_rows<<<dim3(8192), dim3(256), 0, stream>>>(X1, ff_ng, ff_nb, XN);
  gemm8(XN, ffw1T, nullptr, nullptr, 1, Hb, 1, 8192, 4096, 1024);
  gemm(Hb, ffw2T, nullptr, X1, 0, d_out, 0, 8192, 1024, 4096);
}